// Round 1
// 195.182 us; speedup vs baseline: 1.0767x; 1.0767x over previous
//
#include <hip/hip_runtime.h>
#include <cstdint>
#include <cstddef>

// Problem constants (from reference: B,T,N = 512,1024,48)
constexpr int Bb = 512;
constexpr int Tt = 1024;
constexpr int Nn = 48;
constexpr int SG = 16;          // sequences per wave (MFMA M dimension)
constexpr int NG = Bb / SG;     // 32 sequence-groups
constexpr int Cc = 32;          // time-chunks per sequence (grid = NG*Cc = 1024 -> 1 wave/SIMD)
constexpr int Lc = Tt / Cc;     // 32 steps per chunk
constexpr int Wb = 32;          // burn-in steps (R5/R8 validated)
constexpr int AP = 72;          // padded alpha row stride in shorts (144 B = 36 banks)

typedef short bf16x8 __attribute__((ext_vector_type(8)));
typedef float f32x4  __attribute__((ext_vector_type(4)));

__device__ __forceinline__ unsigned short bf16_rne(float x) {
    const unsigned int u = __float_as_uint(x);
    return (unsigned short)((u + 0x7FFFu + ((u >> 16) & 1u)) >> 16);
}
__device__ __forceinline__ float safe_log(float x) {
    return __logf(fmaxf(x, 1e-30f));   // NaN/inf-proof (fmax discards NaN)
}

// ---------------------------------------------------------------------------
// One wave per (16-seq group, time chunk). Cc=32 doubles chunk parallelism
// (1024 waves = 1/SIMD). Gold score for sequence blockIdx.x>>1 (half each,
// h = blockIdx.x&1) fused in.
// Prefetch pipeline rebuilt: 4-slot pbuf with STATIC slot indices via a
// 4x-unrolled step macro -- no register rotation, loads land directly in
// their slot and are consumed 3 iterations later, so the compiler can emit
// counted vmcnt waits. The old asm "memory" fences (which force a vmcnt
// drain every step, killing the prefetch) are replaced by sched_barrier(0)
// pairs that only pin the LDS pack-write -> fragment-read ordering.
// ---------------------------------------------------------------------------
__launch_bounds__(64, 1)
__global__ void crf_fused(const float* __restrict__ pot,
                          const int*   __restrict__ ytrue,
                          const int*   __restrict__ lengths,
                          const float* __restrict__ trans,
                          float*       __restrict__ out)
{
    __shared__ float trans_lds[Nn * Nn];
    __shared__ __align__(16) unsigned short ab[SG][AP];   // alpha, bf16, padded

    const int lane = threadIdx.x;
    const int ln   = lane & 15;          // MFMA free index
    const int q    = lane >> 4;          // quad
    const int gidx = blockIdx.x >> 5;    // sequence group (Cc == 32)
    const int c    = blockIdx.x & 31;    // chunk
    const int s0   = gidx * SG;

    for (int i = lane; i < Nn * Nn; i += 64) trans_lds[i] = trans[i];
    for (int i = lane; i < SG * AP; i += 64) ((unsigned short*)ab)[i] = 0;
    __syncthreads();   // once, outside the loop

    // ---- Gold-path score: sequence b = blockIdx.x>>1, half h = blockIdx.x&1.
    {
        const int    b    = blockIdx.x >> 1;
        const int    h    = blockIdx.x & 1;
        const int    lenb = lengths[b];
        const int*   yrow = ytrue + (size_t)b * Tt;
        const float* prow = pot + (size_t)b * Tt * Nn;
        float gold = 0.0f;
#pragma unroll
        for (int k = 0; k < Tt / 128; ++k) {          // 8 iters x 64 lanes = 512 t
            const int   t    = h * (Tt / 2) + lane + 64 * k;
            const int   yt   = yrow[t];
            const int   ytm1 = yrow[(t > 0) ? (t - 1) : 0];
            const float u    = prow[(size_t)t * Nn + yt];
            const float tr   = trans_lds[ytm1 * Nn + yt];
            gold += (t < lenb) ? u : 0.0f;
            gold += (t >= 1 && t < lenb) ? tr : 0.0f;
        }
#pragma unroll
        for (int off = 32; off > 0; off >>= 1) gold += __shfl_xor(gold, off);
        if (lane == 0) atomicAdd(&out[b], -gold);
    }

    int len4[4];
#pragma unroll
    for (int r = 0; r < 4; ++r) len4[r] = lengths[s0 + q * 4 + r];
    int lmax = lengths[s0 + ln];
#pragma unroll
    for (int off = 8; off > 0; off >>= 1) {
        const int o = __shfl_xor(lmax, off);
        lmax = (o > lmax) ? o : lmax;
    }

    const int start = (c == 0) ? 1 : c * Lc;
    if (c > 0 && start >= lmax) return;          // chunk past every row (gold done)
    const int end = ((c + 1) * Lc < lmax) ? (c + 1) * Lc : lmax;

    // B fragments: Bf[nt][kc][d] = bf16(exp(trans[i][j])), i=kc*32+q*8+d, j=nt*16+ln
    bf16x8 Bf[3][2];
#pragma unroll
    for (int nt = 0; nt < 3; ++nt)
#pragma unroll
        for (int kc = 0; kc < 2; ++kc)
#pragma unroll
            for (int d = 0; d < 8; ++d) {
                const int i = kc * 32 + q * 8 + d;
                const int j = nt * 16 + ln;
                const float v = (i < Nn) ? __expf(trans_lds[i * Nn + j]) : 0.0f;
                Bf[nt][kc][d] = (short)bf16_rne(v);
            }

    const float* pbase[4];
#pragma unroll
    for (int r = 0; r < 4; ++r)
        pbase[r] = pot + (size_t)(s0 + q * 4 + r) * (Tt * Nn) + ln;

    // t0 clamped to >= 1 (with Lc=32, c=1 would otherwise hit t0-1 = -1;
    // clamping to 1 makes c=1 exact: full recompute from alpha0 = pot[0]).
    int t0 = (c == 0) ? 1 : (start - Wb);
    if (t0 < 1) t0 = 1;

    // ---- Init alpha from pot[t0-1], normalized so alpha[m][0] = 1.
    float pinit[3][4];
#pragma unroll
    for (int nt = 0; nt < 3; ++nt)
#pragma unroll
        for (int r = 0; r < 4; ++r)
            pinit[nt][r] = pbase[r][(size_t)(t0 - 1) * Nn + nt * 16];

    float sh4[4];
#pragma unroll
    for (int r = 0; r < 4; ++r) sh4[r] = __shfl(pinit[0][r], lane & 48);  // col-0 lane

    float prev[3][4];
    float gacc[4];
#pragma unroll
    for (int r = 0; r < 4; ++r) gacc[r] = (c == 0) ? sh4[r] : 0.0f;
#pragma unroll
    for (int nt = 0; nt < 3; ++nt)
#pragma unroll
        for (int r = 0; r < 4; ++r) {
            const float v = __expf(pinit[nt][r] - sh4[r]);
            prev[nt][r] = v;
            ab[q * 4 + r][nt * 16 + ln] = bf16_rne(v);
        }
    __builtin_amdgcn_sched_barrier(0);   // pin pack-writes before fragment reads
    bf16x8 A0 = *(const bf16x8*)&ab[ln][q * 8];
    bf16x8 A1 = *(const bf16x8*)&ab[ln][32 + q * 8];
    __builtin_amdgcn_sched_barrier(0);

    // ---- 4-slot prefetch pipeline, statically indexed. pbuf[s] holds raw
    // pot[t] for t = (aligned) t0+k with k%4 == s. epv always holds exp(pot[t])
    // for the CURRENT step, computed one step ahead from a slot loaded 3
    // iterations earlier (real distance-3; no register rotation moves).
    float pbuf[4][3][4];
#pragma unroll
    for (int s = 0; s < 4; ++s) {
        const int ts = (t0 + s < Tt) ? (t0 + s) : (Tt - 1);
#pragma unroll
        for (int nt = 0; nt < 3; ++nt)
#pragma unroll
            for (int r = 0; r < 4; ++r)
                pbuf[s][nt][r] = pbase[r][(size_t)ts * Nn + nt * 16];
    }
    float epv[3][4];
#pragma unroll
    for (int nt = 0; nt < 3; ++nt)
#pragma unroll
        for (int r = 0; r < 4; ++r)
            epv[nt][r] = __expf(pbuf[0][nt][r]);

    // Step count rounded up to a multiple of 4. Extra (<4) steps are safe:
    // any row that is "last" in this chunk has len <= end, hence is frozen
    // (ns = prev) for t >= end; non-frozen rows' prev is never consumed here.
    // gacc is guarded by t < end.
    const int ksteps = ((end - t0) + 3) & ~3;

#define CRF_STEP(KK, SS)                                                        \
    {                                                                           \
        const int t   = t0 + (KK);                                              \
        const int tld = (t + 4 < Tt) ? (t + 4) : (Tt - 1);                      \
        _Pragma("unroll")                                                       \
        for (int nt = 0; nt < 3; ++nt) {                                        \
            _Pragma("unroll")                                                   \
            for (int r = 0; r < 4; ++r)                                         \
                pbuf[SS][nt][r] = pbase[r][(size_t)tld * Nn + nt * 16];         \
        }                                                                       \
        f32x4 D[3];                                                             \
        _Pragma("unroll")                                                       \
        for (int nt = 0; nt < 3; ++nt) {                                        \
            f32x4 z = {0.0f, 0.0f, 0.0f, 0.0f};                                 \
            D[nt] = __builtin_amdgcn_mfma_f32_16x16x32_bf16(A0, Bf[nt][0], z, 0, 0, 0); \
            D[nt] = __builtin_amdgcn_mfma_f32_16x16x32_bf16(A1, Bf[nt][1], D[nt], 0, 0, 0); \
        }                                                                       \
        float vv[3][4];                                                         \
        _Pragma("unroll")                                                       \
        for (int nt = 0; nt < 3; ++nt) {                                        \
            _Pragma("unroll")                                                   \
            for (int r = 0; r < 4; ++r)                                         \
                vv[nt][r] = D[nt][r] * epv[nt][r];                              \
        }                                                                       \
        float c4[4];                                                            \
        _Pragma("unroll")                                                       \
        for (int r = 0; r < 4; ++r) c4[r] = __shfl(vv[0][r], lane & 48);        \
        float rr[4];                                                            \
        _Pragma("unroll")                                                       \
        for (int r = 0; r < 4; ++r) rr[r] = __builtin_amdgcn_rcpf(fmaxf(c4[r], 1e-30f)); \
        _Pragma("unroll")                                                       \
        for (int r = 0; r < 4; ++r) {                                           \
            const float lg = safe_log(c4[r]);                                   \
            gacc[r] += ((t >= start) && (t < len4[r]) && (t < end)) ? lg : 0.0f; \
        }                                                                       \
        _Pragma("unroll")                                                       \
        for (int nt = 0; nt < 3; ++nt) {                                        \
            _Pragma("unroll")                                                   \
            for (int r = 0; r < 4; ++r) {                                       \
                const float ns = (t < len4[r]) ? (vv[nt][r] * rr[r]) : prev[nt][r]; \
                prev[nt][r] = ns;                                               \
                ab[q * 4 + r][nt * 16 + ln] = bf16_rne(ns);                     \
            }                                                                   \
        }                                                                       \
        __builtin_amdgcn_sched_barrier(0);                                      \
        A0 = *(const bf16x8*)&ab[ln][q * 8];                                    \
        A1 = *(const bf16x8*)&ab[ln][32 + q * 8];                               \
        __builtin_amdgcn_sched_barrier(0);                                      \
        _Pragma("unroll")                                                       \
        for (int nt = 0; nt < 3; ++nt) {                                        \
            _Pragma("unroll")                                                   \
            for (int r = 0; r < 4; ++r)                                         \
                epv[nt][r] = __expf(pbuf[((SS) + 1) & 3][nt][r]);               \
        }                                                                       \
    }

    for (int k = 0; k < ksteps; k += 4) {
        CRF_STEP(k + 0, 0);
        CRF_STEP(k + 1, 1);
        CRF_STEP(k + 2, 2);
        CRF_STEP(k + 3, 3);
    }
#undef CRF_STEP

    // Chunk contribution; the unique "last" chunk adds the logsumexp.
    float G[4];
#pragma unroll
    for (int r = 0; r < 4; ++r) {
        float rs = prev[0][r] + prev[1][r] + prev[2][r];
#pragma unroll
        for (int off = 8; off > 0; off >>= 1) rs += __shfl_xor(rs, off);
        const bool active_chunk = (c == 0) || (c * Lc < len4[r]);
        const bool last = active_chunk && (len4[r] <= (c + 1) * Lc);
        const float lgr = safe_log(rs);
        G[r] = gacc[r] + (last ? lgr : 0.0f);
    }
    if (ln == 0) {
#pragma unroll
        for (int r = 0; r < 4; ++r) atomicAdd(&out[s0 + q * 4 + r], G[r]);
    }
}

extern "C" void kernel_launch(void* const* d_in, const int* in_sizes, int n_in,
                              void* d_out, int out_size, void* d_ws, size_t ws_size,
                              hipStream_t stream)
{
    const float* pot   = (const float*)d_in[0];
    const int*   ytrue = (const int*)  d_in[1];
    const int*   lens  = (const int*)  d_in[2];
    const float* trans = (const float*)d_in[3];
    float*       out   = (float*)d_out;

    hipMemsetAsync(out, 0, (size_t)out_size * sizeof(float), stream);
    crf_fused<<<dim3(NG * Cc), dim3(64), 0, stream>>>(pot, ytrue, lens, trans, out);
}

// Round 3
// 181.996 us; speedup vs baseline: 1.1547x; 1.0725x over previous
//
#include <hip/hip_runtime.h>
#include <cstdint>
#include <cstddef>

// Problem constants (from reference: B,T,N = 512,1024,48)
constexpr int Bb = 512;
constexpr int Tt = 1024;
constexpr int Nn = 48;
constexpr int SG = 16;          // sequences per wave (MFMA N dimension here)
constexpr int NG = Bb / SG;     // 32 sequence-groups
constexpr int Cc = 32;          // time-chunks per sequence (grid = 1024 -> 1 wave/SIMD)
constexpr int Lc = Tt / Cc;     // 32 steps per chunk
constexpr int Wb = 32;          // burn-in steps (R5/R8 validated)

typedef short bf16x8 __attribute__((ext_vector_type(8)));
typedef float f32x4  __attribute__((ext_vector_type(4)));
typedef unsigned int u32x4 __attribute__((ext_vector_type(4)));

__device__ __forceinline__ unsigned int bf16_rne(float x) {
    const unsigned int u = __float_as_uint(x);
    return ((u + 0x7FFFu + ((u >> 16) & 1u)) >> 16);
}
__device__ __forceinline__ unsigned int pack2(float lo, float hi) {
    return bf16_rne(lo) | (bf16_rne(hi) << 16);
}
__device__ __forceinline__ float safe_log(float x) {
    return __logf(fmaxf(x, 1e-30f));   // NaN/inf-proof (fmax discards NaN)
}

// ---------------------------------------------------------------------------
// Operand-swapped recurrence: D[j][m] = sum_i E^T[j][i] * alpha[m][i]; the
// E fragment is the MFMA *A* operand and alpha is the *B* operand. Output D:
// seq m = ln (col), state j = 16nt+4q+r (row). Next step's B-fragment needs
// seq = ln (already lane-local) and states at K-slots we may permute, as long
// as A and B use the SAME K-slot->state bijection (fixed this round):
//   kc0 (B0): slot (q,d) -> state 16*(d>>2) + 4q + (d&3)  => B0 = the lane's
//             own packed pk words [pk00,pk01,pk10,pk11] - zero data movement.
//   kc1 (B1): slot (q,d) -> state 32 + 8q + d (q<2; A zero-padded for q>=2)
//             => B1 = {pk20@quad2q, pk21@quad2q, pk20@quad2q+1, pk21@quad2q+1}
//             i.e. 4 bpermute pulls, hidden under MFMA0.
// No LDS in the loop, no fences. Renorm is per-lane uniform (1 rcp/log/bcast
// per step); the division is deferred into the next step's epv multiply, so
// the gacc gate is (t+1 < len): the last active step's log c is captured by
// the final (un-normalized) rowsum. Exact telescoping.
// pot loads: the lane's 12 floats/step are 3 contiguous float4s of row seq=ln
// -> 3 coalesced dwordx4 into 12 NAMED f32x4 prefetch slots (distance 4).
// ---------------------------------------------------------------------------
__launch_bounds__(64, 1)
__global__ void crf_fused(const float* __restrict__ pot,
                          const int*   __restrict__ ytrue,
                          const int*   __restrict__ lengths,
                          const float* __restrict__ trans,
                          float*       __restrict__ out)
{
    __shared__ float trans_lds[Nn * Nn];

    const int lane = threadIdx.x;
    const int ln   = lane & 15;          // sequence index within group (MFMA N)
    const int q    = lane >> 4;          // quad
    const int gidx = blockIdx.x >> 5;    // sequence group (Cc == 32)
    const int c    = blockIdx.x & 31;    // chunk
    const int s0   = gidx * SG;

    for (int i = lane; i < Nn * Nn; i += 64) trans_lds[i] = trans[i];
    __syncthreads();   // once, outside the loop

    // ---- Gold-path score: sequence b = blockIdx.x>>1, half h = blockIdx.x&1.
    {
        const int    b    = blockIdx.x >> 1;
        const int    h    = blockIdx.x & 1;
        const int    lenb = lengths[b];
        const int*   yrow = ytrue + (size_t)b * Tt;
        const float* prow = pot + (size_t)b * Tt * Nn;
        float gold = 0.0f;
#pragma unroll
        for (int k = 0; k < Tt / 128; ++k) {          // 8 iters x 64 lanes = 512 t
            const int   t    = h * (Tt / 2) + lane + 64 * k;
            const int   yt   = yrow[t];
            const int   ytm1 = yrow[(t > 0) ? (t - 1) : 0];
            const float u    = prow[(size_t)t * Nn + yt];
            const float tr   = trans_lds[ytm1 * Nn + yt];
            gold += (t < lenb) ? u : 0.0f;
            gold += (t >= 1 && t < lenb) ? tr : 0.0f;
        }
#pragma unroll
        for (int off = 32; off > 0; off >>= 1) gold += __shfl_xor(gold, off);
        if (lane == 0) atomicAdd(&out[b], -gold);
    }

    const int len_ln = lengths[s0 + ln];         // per-lane sequence length
    int lmax = len_ln;
#pragma unroll
    for (int off = 8; off > 0; off >>= 1) {
        const int o = __shfl_xor(lmax, off);
        lmax = (o > lmax) ? o : lmax;
    }

    const int start = (c == 0) ? 1 : c * Lc;
    if (c > 0 && start >= lmax) return;          // chunk past every row (gold done)
    const int end = ((c + 1) * Lc < lmax) ? (c + 1) * Lc : lmax;

    // A-operand fragments (E^T slices) with the K-slot->state maps above.
    bf16x8 Wf[3][2];
#pragma unroll
    for (int nt = 0; nt < 3; ++nt)
#pragma unroll
        for (int kc = 0; kc < 2; ++kc)
#pragma unroll
            for (int d = 0; d < 8; ++d) {
                int i;
                if (kc == 0) {
                    i = 16 * (d >> 2) + 4 * q + (d & 3);
                } else {
                    i = (q < 2) ? (32 + 8 * q + d) : -1;   // FIXED: identity order,
                                                           // matches B1 shuffle packing
                }
                const float v = (i >= 0) ? __expf(trans_lds[i * Nn + nt * 16 + ln]) : 0.0f;
                Wf[nt][kc][d] = (short)bf16_rne(v);
            }

    // Cross-lane source lanes for B1 words / c broadcast (precomputed once).
    const int slA = ((2 * q) & 3) * 16 + ln;     // quad 2q   (meaningful for q<2)
    const int slB = slA + 16;                    // quad 2q+1
    const int slC = ln;                          // c broadcast: quad-0 lane ln

    // Per-lane pot row (sequence s0+ln); the lane's 3 float4 groups.
    const float* prow = pot + (size_t)(s0 + ln) * (Tt * Nn);
    const float* pp0 = prow + 0 * 16 + q * 4;
    const float* pp1 = prow + 1 * 16 + q * 4;
    const float* pp2 = prow + 2 * 16 + q * 4;

    int t0 = (c == 0) ? 1 : (start - Wb);
    if (t0 < 1) t0 = 1;                          // c=1: exact full recompute

    // ---- Init alpha from pot[t0-1], normalized so alpha[m][0] = 1.
    f32x4 pin0 = *(const f32x4*)(pp0 + (size_t)(t0 - 1) * Nn);
    f32x4 pin1 = *(const f32x4*)(pp1 + (size_t)(t0 - 1) * Nn);
    f32x4 pin2 = *(const f32x4*)(pp2 + (size_t)(t0 - 1) * Nn);
    const float cb0 = __shfl(pin0[0], slC);      // pot[seq ln][state 0]

    float gacc = (c == 0) ? cb0 : 0.0f;          // per-lane (seq = ln)
    f32x4 prev0, prev1, prev2;
#pragma unroll
    for (int r = 0; r < 4; ++r) {
        prev0[r] = __expf(pin0[r] - cb0);
        prev1[r] = __expf(pin1[r] - cb0);
        prev2[r] = __expf(pin2[r] - cb0);
    }

    unsigned int pk00 = pack2(prev0[0], prev0[1]);
    unsigned int pk01 = pack2(prev0[2], prev0[3]);
    unsigned int pk10 = pack2(prev1[0], prev1[1]);
    unsigned int pk11 = pack2(prev1[2], prev1[3]);
    unsigned int pk20 = pack2(prev2[0], prev2[1]);
    unsigned int pk21 = pack2(prev2[2], prev2[3]);
    bf16x8 Bf0 = __builtin_bit_cast(bf16x8, (u32x4){pk00, pk01, pk10, pk11});
    bf16x8 Bf1 = __builtin_bit_cast(bf16x8, (u32x4){
        (unsigned int)__shfl((int)pk20, slA), (unsigned int)__shfl((int)pk21, slA),
        (unsigned int)__shfl((int)pk20, slB), (unsigned int)__shfl((int)pk21, slB)});

    // ---- Named prefetch slots, distance 4: slot s holds pot[t0+s] initially.
    f32x4 P00, P01, P02, P10, P11, P12, P20, P21, P22, P30, P31, P32;
    {
        const size_t ta = (size_t)((t0 + 0 < Tt) ? t0 + 0 : Tt - 1) * Nn;
        const size_t tb = (size_t)((t0 + 1 < Tt) ? t0 + 1 : Tt - 1) * Nn;
        const size_t tc = (size_t)((t0 + 2 < Tt) ? t0 + 2 : Tt - 1) * Nn;
        const size_t td = (size_t)((t0 + 3 < Tt) ? t0 + 3 : Tt - 1) * Nn;
        P00 = *(const f32x4*)(pp0 + ta); P01 = *(const f32x4*)(pp1 + ta); P02 = *(const f32x4*)(pp2 + ta);
        P10 = *(const f32x4*)(pp0 + tb); P11 = *(const f32x4*)(pp1 + tb); P12 = *(const f32x4*)(pp2 + tb);
        P20 = *(const f32x4*)(pp0 + tc); P21 = *(const f32x4*)(pp1 + tc); P22 = *(const f32x4*)(pp2 + tc);
        P30 = *(const f32x4*)(pp0 + td); P31 = *(const f32x4*)(pp1 + td); P32 = *(const f32x4*)(pp2 + td);
    }
    f32x4 epv0, epv1, epv2;      // exp(pot[t]) * pending-renorm, current step
#pragma unroll
    for (int r = 0; r < 4; ++r) {
        epv0[r] = __expf(P00[r]);
        epv1[r] = __expf(P01[r]);
        epv2[r] = __expf(P02[r]);
    }

    const int ksteps = ((end - t0) + 3) & ~3;    // padded steps provably inert

#define CRF_STEP(KK, LA0, LA1, LA2, NB0, NB1, NB2)                              \
    {                                                                           \
        const int t   = t0 + (KK);                                              \
        const size_t tld = (size_t)((t + 4 < Tt) ? (t + 4) : (Tt - 1)) * Nn;    \
        LA0 = *(const f32x4*)(pp0 + tld);                                       \
        LA1 = *(const f32x4*)(pp1 + tld);                                       \
        LA2 = *(const f32x4*)(pp2 + tld);                                       \
        f32x4 z = {0.0f, 0.0f, 0.0f, 0.0f};                                     \
        f32x4 D0 = __builtin_amdgcn_mfma_f32_16x16x32_bf16(Wf[0][0], Bf0, z, 0, 0, 0); \
        f32x4 D1 = __builtin_amdgcn_mfma_f32_16x16x32_bf16(Wf[1][0], Bf0, z, 0, 0, 0); \
        f32x4 D2 = __builtin_amdgcn_mfma_f32_16x16x32_bf16(Wf[2][0], Bf0, z, 0, 0, 0); \
        D0 = __builtin_amdgcn_mfma_f32_16x16x32_bf16(Wf[0][1], Bf1, D0, 0, 0, 0); \
        D1 = __builtin_amdgcn_mfma_f32_16x16x32_bf16(Wf[1][1], Bf1, D1, 0, 0, 0); \
        D2 = __builtin_amdgcn_mfma_f32_16x16x32_bf16(Wf[2][1], Bf1, D2, 0, 0, 0); \
        f32x4 a0, a1, a2;                                                       \
        _Pragma("unroll")                                                       \
        for (int r = 0; r < 4; ++r) {                                           \
            a0[r] = D0[r] * epv0[r];                                            \
            a1[r] = D1[r] * epv1[r];                                            \
            a2[r] = D2[r] * epv2[r];                                            \
        }                                                                       \
        const float cb = __shfl(a0[0], slC);                                    \
        const float rr = __builtin_amdgcn_rcpf(fmaxf(cb, 1e-30f));              \
        const float lg = safe_log(cb);                                          \
        gacc += ((t >= start) && (t < end) && (t + 1 < len_ln)) ? lg : 0.0f;    \
        const bool act = (t < len_ln);                                          \
        _Pragma("unroll")                                                       \
        for (int r = 0; r < 4; ++r) {                                           \
            prev0[r] = act ? a0[r] : prev0[r];                                  \
            prev1[r] = act ? a1[r] : prev1[r];                                  \
            prev2[r] = act ? a2[r] : prev2[r];                                  \
        }                                                                       \
        pk00 = pack2(prev0[0], prev0[1]);                                       \
        pk01 = pack2(prev0[2], prev0[3]);                                       \
        pk10 = pack2(prev1[0], prev1[1]);                                       \
        pk11 = pack2(prev1[2], prev1[3]);                                       \
        pk20 = pack2(prev2[0], prev2[1]);                                       \
        pk21 = pack2(prev2[2], prev2[3]);                                       \
        Bf0 = __builtin_bit_cast(bf16x8, (u32x4){pk00, pk01, pk10, pk11});      \
        Bf1 = __builtin_bit_cast(bf16x8, (u32x4){                               \
            (unsigned int)__shfl((int)pk20, slA), (unsigned int)__shfl((int)pk21, slA), \
            (unsigned int)__shfl((int)pk20, slB), (unsigned int)__shfl((int)pk21, slB)}); \
        _Pragma("unroll")                                                       \
        for (int r = 0; r < 4; ++r) {                                           \
            epv0[r] = __expf(NB0[r]) * rr;                                      \
            epv1[r] = __expf(NB1[r]) * rr;                                      \
            epv2[r] = __expf(NB2[r]) * rr;                                      \
        }                                                                       \
    }

    for (int k = 0; k < ksteps; k += 4) {
        CRF_STEP(k + 0, P00, P01, P02, P10, P11, P12);
        CRF_STEP(k + 1, P10, P11, P12, P20, P21, P22);
        CRF_STEP(k + 2, P20, P21, P22, P30, P31, P32);
        CRF_STEP(k + 3, P30, P31, P32, P00, P01, P02);
    }
#undef CRF_STEP

    // Chunk contribution; the unique "last" chunk adds the logsumexp.
    // (final rowsum is pre-division by the last active step's c, whose log
    //  was deliberately NOT added to gacc - exact telescoping.)
    float rs = prev0[0] + prev0[1] + prev0[2] + prev0[3]
             + prev1[0] + prev1[1] + prev1[2] + prev1[3]
             + prev2[0] + prev2[1] + prev2[2] + prev2[3];
    rs += __shfl_xor(rs, 16);
    rs += __shfl_xor(rs, 32);                    // full 48-state sum per lane

    const bool active_chunk = (c == 0) || (c * Lc < len_ln);
    const bool last = active_chunk && (len_ln <= (c + 1) * Lc);
    const float G = gacc + (last ? safe_log(rs) : 0.0f);
    if (lane < 16) atomicAdd(&out[s0 + ln], G);
}

extern "C" void kernel_launch(void* const* d_in, const int* in_sizes, int n_in,
                              void* d_out, int out_size, void* d_ws, size_t ws_size,
                              hipStream_t stream)
{
    const float* pot   = (const float*)d_in[0];
    const int*   ytrue = (const int*)  d_in[1];
    const int*   lens  = (const int*)  d_in[2];
    const float* trans = (const float*)d_in[3];
    float*       out   = (float*)d_out;

    hipMemsetAsync(out, 0, (size_t)out_size * sizeof(float), stream);
    crf_fused<<<dim3(NG * Cc), dim3(64), 0, stream>>>(pot, ytrue, lens, trans, out);
}